// Round 13
// baseline (320.974 us; speedup 1.0000x reference)
//
#include <hip/hip_runtime.h>
#include <hip/hip_bf16.h>

#define NPIX 32768
#define DCH 512
#define HWSZ 1024
#define WSQ (DCH * DCH)
#define WTR (3 * DCH * 3 * DCH)

typedef __bf16 bf16x8_t __attribute__((ext_vector_type(8)));
typedef float f32x4_t __attribute__((ext_vector_type(4)));
typedef float f32x16_t __attribute__((ext_vector_type(16)));
typedef int i32x4_t __attribute__((ext_vector_type(4)));
typedef int i32x8_t __attribute__((ext_vector_type(8)));
typedef unsigned short u16x8_t __attribute__((ext_vector_type(8)));
typedef unsigned short u16x4_t __attribute__((ext_vector_type(4)));

static __device__ __forceinline__ unsigned short f2bf(float f) {
    return __builtin_bit_cast(unsigned short, __float2bfloat16(f));
}
static __device__ __forceinline__ float bf2f(unsigned short u) {
    unsigned v = (unsigned)u << 16;
    return __builtin_bit_cast(float, v);
}

// ---------------------------------------------------------------------------
// Weights fp32 -> bf16 (blocks [0,NB)) AND fp8 e4m3 (blocks [NB,2NB)),
// last block copies biases. Order: in1,in2,in3, tr, o1,o2,o3.
// ---------------------------------------------------------------------------
__global__ __launch_bounds__(256)
void cvt_all(const float* __restrict__ w0, const float* __restrict__ w1,
             const float* __restrict__ w2, const float* __restrict__ w3,
             const float* __restrict__ w4, const float* __restrict__ w5,
             const float* __restrict__ w6,
             __hip_bfloat16* __restrict__ d, unsigned char* __restrict__ d8,
             const float* __restrict__ b0, const float* __restrict__ b1,
             const float* __restrict__ b2, const float* __restrict__ b3,
             const float* __restrict__ b4, const float* __restrict__ b5,
             float* __restrict__ biasd)
{
    const int NB = (6 * WSQ + WTR) >> 10;
    const int bid = blockIdx.x;
    if (bid == 2 * NB) {
        for (int idx = threadIdx.x; idx < 3072; idx += 256) {
            const int r = idx >> 9, off = idx & 511;
            const float* s = (r == 0) ? b0 : (r == 1) ? b1 : (r == 2) ? b2
                           : (r == 3) ? b3 : (r == 4) ? b4 : b5;
            biasd[idx] = s[off];
        }
        return;
    }
    const bool do8 = (bid >= NB);
    const int i = ((do8 ? bid - NB : bid) * 256 + threadIdx.x) * 4;
    const float* src;
    int off;
    if (i < 3 * WSQ) {
        int r = i >> 18;
        src = (r == 0) ? w0 : ((r == 1) ? w1 : w2);
        off = i - r * WSQ;
    } else if (i < 3 * WSQ + WTR) {
        src = w3; off = i - 3 * WSQ;
    } else {
        int j = i - 3 * WSQ - WTR;
        int r = j >> 18;
        src = (r == 0) ? w4 : ((r == 1) ? w5 : w6);
        off = j - r * WSQ;
    }
    float4 f = *(const float4*)(src + off);
    if (do8) {
        int dw = __builtin_amdgcn_cvt_pk_fp8_f32(f.x, f.y, 0, false);
        dw     = __builtin_amdgcn_cvt_pk_fp8_f32(f.z, f.w, dw, true);
        *(int*)(d8 + i) = dw;
    } else {
        u16x4_t v;
        v[0] = f2bf(f.x); v[1] = f2bf(f.y); v[2] = f2bf(f.z); v[3] = f2bf(f.w);
        *(u16x4_t*)((unsigned short*)d + i) = v;
    }
}

// ---------------------------------------------------------------------------
// Stage: X[b][c][hw] fp32 -> [br][n][c], bf16 (emitbf) and/or fp8 (emit8).
// ---------------------------------------------------------------------------
__global__ __launch_bounds__(256)
void stage_transpose(const float* __restrict__ x0, const float* __restrict__ x1,
                     const float* __restrict__ x2,
                     const float* __restrict__ gp0, const float* __restrict__ gp1,
                     const float* __restrict__ gp2,
                     __hip_bfloat16* __restrict__ XbT,
                     unsigned char* __restrict__ Xb8, int emitbf, int emit8)
{
    __shared__ float tile[64][65];
    const int hw0 = blockIdx.x * 64;
    const int c0  = blockIdx.y * 64;
    const int bz  = blockIdx.z;
    const int br  = bz >> 5;
    const int b   = bz & 31;
    const float* x = (br == 0) ? x0 : ((br == 1) ? x1 : x2);
    const float g  = ((br == 0) ? gp0 : ((br == 1) ? gp1 : gp2))[0];
    const int t = threadIdx.x;

    // read phase: float4 along hw (coalesced)
    const int qh = (t & 15) * 4;
    const int rb = t >> 4;
    const float* src = x + (size_t)b * (DCH * HWSZ) + (size_t)c0 * HWSZ + hw0;
#pragma unroll
    for (int i = 0; i < 4; ++i) {
        const int ci = rb + i * 16;
        float4 v = *(const float4*)(src + (size_t)ci * HWSZ + qh);
        v.x *= g; v.y *= g; v.z *= g; v.w *= g;
        *(float4*)&tile[ci][qh] = v;
    }
    __syncthreads();

    // write phase: one tile-read pass
    const int hwr = t >> 2;
    const int cch = (t & 3) * 16;
    const size_t nrow = (size_t)br * NPIX + b * HWSZ + hw0 + hwr;
    float vals[16];
#pragma unroll
    for (int e = 0; e < 16; ++e) vals[e] = tile[cch + e][hwr];

    if (emitbf) {
        __hip_bfloat16* dst = XbT + nrow * DCH + c0 + cch;
        u16x8_t v0, v1;
#pragma unroll
        for (int e = 0; e < 8; ++e) v0[e] = f2bf(vals[e]);
#pragma unroll
        for (int e = 0; e < 8; ++e) v1[e] = f2bf(vals[8 + e]);
        *(u16x8_t*)dst = v0;
        *((u16x8_t*)dst + 1) = v1;
    }
    if (emit8) {
        i32x4_t w;
#pragma unroll
        for (int q = 0; q < 4; ++q) {
            int dw = __builtin_amdgcn_cvt_pk_fp8_f32(vals[4 * q], vals[4 * q + 1], 0, false);
            dw     = __builtin_amdgcn_cvt_pk_fp8_f32(vals[4 * q + 2], vals[4 * q + 3], dw, true);
            w[q] = dw;
        }
        *(i32x4_t*)(Xb8 + nrow * DCH + c0 + cch) = w;
    }
}

// ---------------------------------------------------------------------------
// gemm_f8: 256x128 tile, 4 waves (2x2), per-wave 128x64 (8 MFMA/K-tile),
// MX-fp8 32x32x64. 3-deep LDS pipeline (72KB, 2 blocks/CU), counted vmcnt(6).
// cmode: 0 = bf16 n-major, 1 = fp8 n-major, 2 = bf16 CHANNEL-major
// (smem-transposed epilogue; ldc = n-dim stride, e.g. NPIX).
// ---------------------------------------------------------------------------
struct pair4 { i32x4_t lo, hi; };

__global__ __launch_bounds__(256, 2)
void gemm_f8(const unsigned char* __restrict__ A, int lda,
             const unsigned char* __restrict__ B, int ldb,
             const float* __restrict__ bias,
             void* __restrict__ Cv, int ldc, int coff0,
             int K, int NO, int TPB, int brA, int brB,
             int bstride, int cstride, int cmode)
{
    __shared__ __align__(16) unsigned char smem[73728];   // 3 x (16K A + 8K B)
    const int tid  = threadIdx.x;
    const int lane = tid & 63;
    const int wave = tid >> 6;
    const int wm = wave >> 1, wn = wave & 1;
    const int l31 = lane & 31;
    const int h   = lane >> 5;

    const int per  = gridDim.x >> 3;
    const int flat = (blockIdx.x & 7) * per + (blockIdx.x >> 3);
    const int br   = flat / TPB;
    const int rem  = flat - br * TPB;
    const int nt = rem / NO, ot = rem % NO;
    const int n0 = nt * 256, o0 = ot * 128;
    const int NT = K >> 6;

    A    += (size_t)br * (size_t)brA;
    B    += (size_t)br * (size_t)brB;
    bias += br * bstride;
    const int coff = coff0 + br * cstride;

    auto stage = [&](int t, unsigned bufb) {
#pragma unroll
        for (int p = 0; p < 6; ++p) {
            const int f = tid + p * 256;
            if (p < 4) {
                const int row = f >> 2, cidx = f & 3;
                const int gch = ((cidx ^ (row & 3) ^ ((row >> 2) & 3)) << 4);
                const unsigned char* ga = A + (size_t)(n0 + row) * lda + t * 64 + gch;
                __builtin_amdgcn_global_load_lds(
                    (const __attribute__((address_space(1))) unsigned int*)ga,
                    (__attribute__((address_space(3))) unsigned int*)(smem + bufb + f * 16),
                    16, 0, 0);
            } else {
                const int fb = f - 1024;
                const int row = fb >> 2, cidx = fb & 3;
                const int gch = ((cidx ^ (row & 3) ^ ((row >> 2) & 3)) << 4);
                const unsigned char* gb = B + (size_t)(o0 + row) * ldb + t * 64 + gch;
                __builtin_amdgcn_global_load_lds(
                    (const __attribute__((address_space(1))) unsigned int*)gb,
                    (__attribute__((address_space(3))) unsigned int*)(smem + bufb + 16384u + fb * 16),
                    16, 0, 0);
            }
        }
    };

#define DSR(dst, a) asm volatile("ds_read_b128 %0, %1" : "=v"(dst) : "v"(a))

    f32x16_t acc[4][2];
#pragma unroll
    for (int mf = 0; mf < 4; ++mf)
#pragma unroll
        for (int nf = 0; nf < 2; ++nf)
#pragma unroll
            for (int e = 0; e < 16; ++e) acc[mf][nf][e] = 0.f;

    unsigned addrA[4], addrB[2];
#pragma unroll
    for (int mf = 0; mf < 4; ++mf) {
        const int r = wm * 128 + mf * 32 + l31;
        const int s = (r & 3) ^ ((r >> 2) & 3);
        addrA[mf] = (unsigned)(r << 6) + (unsigned)((((h << 1)) ^ s) << 4);
    }
#pragma unroll
    for (int nf = 0; nf < 2; ++nf) {
        const int rb = wn * 64 + nf * 32 + l31;
        const int s = (rb & 3) ^ ((rb >> 2) & 3);
        addrB[nf] = 16384u + (unsigned)(rb << 6) + (unsigned)((((h << 1)) ^ s) << 4);
    }

    stage(0, 0u); stage(1, 24576u);
    asm volatile("s_waitcnt vmcnt(6)");
    __builtin_amdgcn_s_barrier();

    unsigned cur = 0u, nxt = 24576u, thr = 49152u;
    for (int t = 0; t < NT; ++t) {
        if (t + 2 < NT) stage(t + 2, thr);

        pair4 a_[4], b_[2];
#pragma unroll
        for (int mf = 0; mf < 4; ++mf) {
            DSR(a_[mf].lo, cur + addrA[mf]);
            DSR(a_[mf].hi, (cur + addrA[mf]) ^ 16u);
        }
#pragma unroll
        for (int nf = 0; nf < 2; ++nf) {
            DSR(b_[nf].lo, cur + addrB[nf]);
            DSR(b_[nf].hi, (cur + addrB[nf]) ^ 16u);
        }
        asm volatile("s_waitcnt lgkmcnt(0)");
        __builtin_amdgcn_sched_barrier(0);

        __builtin_amdgcn_s_setprio(1);
#pragma unroll
        for (int mf = 0; mf < 4; ++mf)
#pragma unroll
            for (int nf = 0; nf < 2; ++nf)
                acc[mf][nf] = __builtin_amdgcn_mfma_scale_f32_32x32x64_f8f6f4(
                    __builtin_bit_cast(i32x8_t, a_[mf]),
                    __builtin_bit_cast(i32x8_t, b_[nf]), acc[mf][nf],
                    0, 0, 0, 0x7F7F7F7F, 0, 0x7F7F7F7F);
        __builtin_amdgcn_s_setprio(0);

        if (t + 2 < NT)      { asm volatile("s_waitcnt vmcnt(6)"); }
        else if (t + 1 < NT) { asm volatile("s_waitcnt vmcnt(0)"); }
        __builtin_amdgcn_s_barrier();
        const unsigned tmp = cur; cur = nxt; nxt = thr; thr = tmp;
    }
#undef DSR

    // C/D 32x32 layout: col = lane&31, row = (rg&3) + 8*(rg>>2) + 4*(lane>>5)
    if (cmode == 0) {
        __hip_bfloat16* C = (__hip_bfloat16*)Cv;
#pragma unroll
        for (int nf = 0; nf < 2; ++nf) {
            const int col = o0 + wn * 64 + nf * 32 + l31;
            const float bv = bias[col];
#pragma unroll
            for (int mf = 0; mf < 4; ++mf)
#pragma unroll
                for (int rg = 0; rg < 16; ++rg) {
                    const int row = n0 + wm * 128 + mf * 32 + (rg & 3) + ((rg >> 2) << 3) + (h << 2);
                    C[(size_t)row * ldc + coff + col] = __float2bfloat16(acc[mf][nf][rg] + bv);
                }
        }
    } else if (cmode == 1) {
        unsigned char* C8 = (unsigned char*)Cv;
#pragma unroll
        for (int nf = 0; nf < 2; ++nf) {
            const int col = o0 + wn * 64 + nf * 32 + l31;
            const float bv = bias[col];
#pragma unroll
            for (int mf = 0; mf < 4; ++mf)
#pragma unroll
                for (int q = 0; q < 4; ++q) {
                    int dw = __builtin_amdgcn_cvt_pk_fp8_f32(acc[mf][nf][4 * q] + bv,
                                                             acc[mf][nf][4 * q + 1] + bv, 0, false);
                    dw     = __builtin_amdgcn_cvt_pk_fp8_f32(acc[mf][nf][4 * q + 2] + bv,
                                                             acc[mf][nf][4 * q + 3] + bv, dw, true);
                    const int row = n0 + wm * 128 + mf * 32 + 8 * q + (h << 2);
                    const size_t base = (size_t)row * ldc + coff + col;
                    const unsigned u = (unsigned)dw;
                    C8[base]           = (unsigned char)u;
                    C8[base + ldc]     = (unsigned char)(u >> 8);
                    C8[base + 2 * ldc] = (unsigned char)(u >> 16);
                    C8[base + 3 * ldc] = (unsigned char)(u >> 24);
                }
        }
    } else {
        // cmode == 2: channel-major bf16 via smem transpose (64KB <= 72KB)
        __hip_bfloat16* C = (__hip_bfloat16*)Cv;
        __syncthreads();
#pragma unroll
        for (int nf = 0; nf < 2; ++nf) {
            const int cl = wn * 64 + nf * 32 + l31;            // 0..127
            const float bv = bias[o0 + cl];
            const unsigned sw = ((unsigned)(cl & 7)) << 4;
#pragma unroll
            for (int mf = 0; mf < 4; ++mf)
#pragma unroll
                for (int rg = 0; rg < 16; ++rg) {
                    const int r = wm * 128 + mf * 32 + (rg & 3) + ((rg >> 2) << 3) + (h << 2);
                    *(unsigned short*)(smem + (unsigned)cl * 512u + (((unsigned)r * 2u) ^ sw)) =
                        f2bf(acc[mf][nf][rg] + bv);
                }
        }
        __syncthreads();
        const int cl   = tid >> 1;
        const int half = tid & 1;
        const unsigned sw = ((unsigned)(cl & 7)) << 4;
        __hip_bfloat16* dst = C + (size_t)(coff + o0 + cl) * (size_t)ldc + n0 + half * 128;
#pragma unroll
        for (int j8 = 0; j8 < 16; ++j8) {
            const unsigned byteL = (unsigned)cl * 512u
                + ((((unsigned)(half * 128 + j8 * 8)) * 2u) ^ sw);
            *(u16x8_t*)((unsigned short*)dst + j8 * 8) = *(const u16x8_t*)(smem + byteL);
        }
    }
}

// ---------------------------------------------------------------------------
// 256x256 bf16 NT GEMM (fallback path only; R7 structure).
// ---------------------------------------------------------------------------
__global__ __launch_bounds__(512, 2)
void gemm256(const __hip_bfloat16* __restrict__ A, int lda,
             const __hip_bfloat16* __restrict__ B, int ldb,
             const float* __restrict__ bias,
             __hip_bfloat16* __restrict__ C, int ldc, int coff0,
             int K, int NO, int TPB, int brA, int brB, int bstride,
             int cstride, int trans_out)
{
    __shared__ __align__(16) unsigned char smem[131072];
    const int tid  = threadIdx.x;
    const int lane = tid & 63;
    const int wave = tid >> 6;
    const int wm   = wave >> 2;
    const int wn   = wave & 3;
    const int l16  = lane & 15;
    const int l4   = lane >> 4;

    const int per  = gridDim.x >> 3;
    const int flat = (blockIdx.x & 7) * per + (blockIdx.x >> 3);
    const int br   = flat / TPB;
    const int rem  = flat - br * TPB;
    const int nt   = rem / NO;
    const int ot   = rem - nt * NO;
    const int n0 = nt * 256;
    const int o0 = ot * 256;
    const int NT = K >> 6;

    A    += (size_t)br * (size_t)brA;
    B    += (size_t)br * (size_t)brB;
    bias += br * bstride;
    const int coff = coff0 + br * cstride;

    const unsigned xorv = (unsigned)((l16 & 7) << 4);
    unsigned baseA[2], baseB[2];
#pragma unroll
    for (int kk = 0; kk < 2; ++kk) {
        const unsigned ko = ((unsigned)(kk * 64 + l4 * 16)) ^ xorv;
        baseA[kk] = (unsigned)((wm * 128 + l16) * 128) + ko;
        baseB[kk] = 32768u + (unsigned)((wn * 64 + l16) * 128) + ko;
    }

    const int rr  = lane >> 3;
    const int kel = 8 * ((lane & 7) ^ rr);

    auto stageA = [&](int t, int half) {
        const unsigned dst = (unsigned)((t & 1) * 65536 + half * 16384 + wave * 2048);
        const __hip_bfloat16* g = A + (size_t)(n0 + half * 128 + wave * 16 + rr) * lda + t * 64 + kel;
#pragma unroll
        for (int s = 0; s < 2; ++s) {
            __builtin_amdgcn_global_load_lds(
                (const __attribute__((address_space(1))) unsigned int*)(g + (size_t)s * 8 * lda),
                (__attribute__((address_space(3))) unsigned int*)(smem + dst + s * 1024),
                16, 0, 0);
        }
    };
    auto stageB = [&](int t, int half) {
        const unsigned dst = (unsigned)((t & 1) * 65536 + 32768 + half * 16384 + wave * 2048);
        const __hip_bfloat16* g = B + (size_t)(o0 + half * 128 + wave * 16 + rr) * ldb + t * 64 + kel;
#pragma unroll
        for (int s = 0; s < 2; ++s) {
            __builtin_amdgcn_global_load_lds(
                (const __attribute__((address_space(1))) unsigned int*)(g + (size_t)s * 8 * ldb),
                (__attribute__((address_space(3))) unsigned int*)(smem + dst + s * 1024),
                16, 0, 0);
        }
    };

#define DSRO(dst, addr, OFF) \
    asm volatile("ds_read_b128 %0, %1 offset:" #OFF : "=v"(dst) : "v"(addr))
#define BC(x) __builtin_bit_cast(bf16x8_t, x)

    stageA(0, 0); stageA(0, 1); stageB(0, 0); stageB(0, 1);
    stageA(1, 0); stageA(1, 1); stageB(1, 0); stageB(1, 1);
    asm volatile("s_waitcnt vmcnt(8)");
    __builtin_amdgcn_s_barrier();

    f32x4_t aR[4][2], a2[4][2], bA[2][2], bB[2][2];
    f32x4_t acc[8][4];
#pragma unroll
    for (int m = 0; m < 8; ++m)
#pragma unroll
        for (int n = 0; n < 4; ++n) acc[m][n] = (f32x4_t){0.f, 0.f, 0.f, 0.f};

    {
        unsigned a0 = baseA[0], a1 = baseA[1], b0 = baseB[0], b1 = baseB[1];
        DSRO(aR[0][0], a0, 0);    DSRO(aR[1][0], a0, 2048);
        DSRO(aR[2][0], a0, 4096); DSRO(aR[3][0], a0, 6144);
        DSRO(aR[0][1], a1, 0);    DSRO(aR[1][1], a1, 2048);
        DSRO(aR[2][1], a1, 4096); DSRO(aR[3][1], a1, 6144);
        DSRO(bA[0][0], b0, 0);    DSRO(bA[1][0], b0, 2048);
        DSRO(bA[0][1], b1, 0);    DSRO(bA[1][1], b1, 2048);
    }

    unsigned cb = 0;
    for (int t = 0; t < NT; ++t) {
        const unsigned cbn = cb ^ 65536u;
        const unsigned a0 = cb + baseA[0], a1 = cb + baseA[1];
        const unsigned b0 = cb + baseB[0], b1 = cb + baseB[1];

        asm volatile("s_waitcnt lgkmcnt(0)");
        __builtin_amdgcn_sched_barrier(0);
        DSRO(bB[0][0], b0, 4096); DSRO(bB[1][0], b0, 6144);
        DSRO(bB[0][1], b1, 4096); DSRO(bB[1][1], b1, 6144);
        __builtin_amdgcn_sched_barrier(0);
        __builtin_amdgcn_s_setprio(1);
#pragma unroll
        for (int m = 0; m < 4; ++m)
#pragma unroll
            for (int n = 0; n < 2; ++n)
#pragma unroll
                for (int kk = 0; kk < 2; ++kk)
                    acc[m][n] = __builtin_amdgcn_mfma_f32_16x16x32_bf16(BC(aR[m][kk]), BC(bA[n][kk]), acc[m][n], 0, 0, 0);
        __builtin_amdgcn_s_setprio(0);
        __builtin_amdgcn_s_barrier();

        asm volatile("s_waitcnt lgkmcnt(0)");
        __builtin_amdgcn_sched_barrier(0);
        DSRO(a2[0][0], a0, 8192);  DSRO(a2[1][0], a0, 10240);
        DSRO(a2[2][0], a0, 12288); DSRO(a2[3][0], a0, 14336);
        DSRO(a2[0][1], a1, 8192);  DSRO(a2[1][1], a1, 10240);
        DSRO(a2[2][1], a1, 12288); DSRO(a2[3][1], a1, 14336);
        __builtin_amdgcn_sched_barrier(0);
        __builtin_amdgcn_s_setprio(1);
#pragma unroll
        for (int m = 0; m < 4; ++m)
#pragma unroll
            for (int n = 0; n < 2; ++n)
#pragma unroll
                for (int kk = 0; kk < 2; ++kk)
                    acc[m][n + 2] = __builtin_amdgcn_mfma_f32_16x16x32_bf16(BC(aR[m][kk]), BC(bB[n][kk]), acc[m][n + 2], 0, 0, 0);
        __builtin_amdgcn_s_setprio(0);
        __builtin_amdgcn_s_barrier();

        asm volatile("s_waitcnt lgkmcnt(0)");
        __builtin_amdgcn_sched_barrier(0);
        if (t + 2 < NT) { stageB(t + 2, 0); stageB(t + 2, 1); }
        __builtin_amdgcn_sched_barrier(0);
        __builtin_amdgcn_s_setprio(1);
#pragma unroll
        for (int m = 0; m < 4; ++m)
#pragma unroll
            for (int n = 0; n < 2; ++n)
#pragma unroll
                for (int kk = 0; kk < 2; ++kk)
                    acc[m + 4][n] = __builtin_amdgcn_mfma_f32_16x16x32_bf16(BC(a2[m][kk]), BC(bA[n][kk]), acc[m + 4][n], 0, 0, 0);
        __builtin_amdgcn_s_setprio(0);
        if (t + 2 < NT)        { asm volatile("s_waitcnt vmcnt(4)"); }
        else if (t + 2 == NT)  { asm volatile("s_waitcnt vmcnt(0)"); }
        __builtin_amdgcn_s_barrier();

        if (t + 1 < NT) {
            const unsigned na0 = cbn + baseA[0], na1 = cbn + baseA[1];
            const unsigned nb0 = cbn + baseB[0], nb1 = cbn + baseB[1];
            DSRO(aR[0][0], na0, 0);    DSRO(aR[1][0], na0, 2048);
            DSRO(aR[2][0], na0, 4096); DSRO(aR[3][0], na0, 6144);
            DSRO(aR[0][1], na1, 0);    DSRO(aR[1][1], na1, 2048);
            DSRO(aR[2][1], na1, 4096); DSRO(aR[3][1], na1, 6144);
            DSRO(bA[0][0], nb0, 0);    DSRO(bA[1][0], nb0, 2048);
            DSRO(bA[0][1], nb1, 0);    DSRO(bA[1][1], nb1, 2048);
        }
        if (t + 2 < NT) { stageA(t + 2, 0); stageA(t + 2, 1); }
        __builtin_amdgcn_sched_barrier(0);
        __builtin_amdgcn_s_setprio(1);
#pragma unroll
        for (int m = 0; m < 4; ++m)
#pragma unroll
            for (int n = 0; n < 2; ++n)
#pragma unroll
                for (int kk = 0; kk < 2; ++kk)
                    acc[m + 4][n + 2] = __builtin_amdgcn_mfma_f32_16x16x32_bf16(BC(a2[m][kk]), BC(bB[n][kk]), acc[m + 4][n + 2], 0, 0, 0);
        __builtin_amdgcn_s_setprio(0);
        cb = cbn;
    }

    if (!trans_out) {
#pragma unroll
        for (int n = 0; n < 4; ++n) {
            const int oc = o0 + wn * 64 + n * 16 + l16;
            const float bv = bias[oc];
#pragma unroll
            for (int m = 0; m < 8; ++m)
#pragma unroll
                for (int r = 0; r < 4; ++r) {
                    const int nr = n0 + wm * 128 + m * 16 + l4 * 4 + r;
                    C[(size_t)nr * ldc + coff + oc] = __float2bfloat16(acc[m][n][r] + bv);
                }
        }
    } else {
        __syncthreads();
#pragma unroll
        for (int n = 0; n < 4; ++n) {
            const int ocl = wn * 64 + n * 16 + l16;
            const float bv = bias[o0 + ocl];
#pragma unroll
            for (int m = 0; m < 8; ++m)
#pragma unroll
                for (int r = 0; r < 4; ++r) {
                    const int nrow = wm * 128 + m * 16 + l4 * 4 + r;
                    const unsigned phys = (unsigned)nrow * 512u
                        + (((unsigned)ocl * 2u) ^ (((unsigned)(nrow & 7)) << 4));
                    *(unsigned short*)(smem + phys) = f2bf(acc[m][n][r] + bv);
                }
        }
        __syncthreads();
        const int ol = tid >> 1;
        const int nh = (tid & 1) * 128;
        __hip_bfloat16* dst = C + (size_t)(coff + o0 + ol) * ldc + n0 + nh;
#pragma unroll
        for (int j8 = 0; j8 < 16; ++j8) {
            u16x8_t v;
#pragma unroll
            for (int e = 0; e < 8; ++e) {
                const int n2 = nh + j8 * 8 + e;
                v[e] = *(const unsigned short*)(smem + (unsigned)n2 * 512u
                        + ((((unsigned)ol * 2u) ^ ((unsigned)e << 4))));
            }
            *(u16x8_t*)((unsigned short*)dst + j8 * 8) = v;
        }
    }
#undef DSRO
#undef BC
}

// ---------------------------------------------------------------------------
// final_fuse: G channel-major [1536][NPIX] bf16, x fp32 natural layout.
// ---------------------------------------------------------------------------
__global__ __launch_bounds__(256)
void final_fuse(const __hip_bfloat16* __restrict__ G,
                const float* __restrict__ x0, const float* __restrict__ x1,
                const float* __restrict__ x2,
                const float* __restrict__ gp0, const float* __restrict__ gp1,
                const float* __restrict__ gp2,
                float* __restrict__ out)
{
    const int n  = blockIdx.x * 256 + threadIdx.x;
    const int b  = n >> 10;
    const int hw = n & (HWSZ - 1);
    const int c0 = blockIdx.y * 64;
    const float ga0 = gp0[0], ga1 = gp1[0], ga2 = gp2[0];
    for (int cc = 0; cc < 64; ++cc) {
        const int c = c0 + cc;
        const float s0 = __bfloat162float(G[(size_t)c * NPIX + n]);
        const float s1 = __bfloat162float(G[(size_t)(c + DCH) * NPIX + n]);
        const float s2 = __bfloat162float(G[(size_t)(c + 2 * DCH) * NPIX + n]);
        const float g0v = 1.0f / (1.0f + __expf(-s0));
        const float g1v = 1.0f / (1.0f + __expf(-s1));
        const float g2v = 1.0f / (1.0f + __expf(-s2));
        const float e0 = __expf(g0v), e1 = __expf(g1v), e2 = __expf(g2v);
        const float inv = 1.0f / (e0 + e1 + e2);
        const size_t xo = (size_t)b * (DCH * HWSZ) + (size_t)c * HWSZ + hw;
        out[xo] = inv * (e0 * ga0 * x0[xo] + e1 * ga1 * x1[xo] + e2 * ga2 * x2[xo]);
    }
}

// ---------------------------------------------------------------------------
extern "C" void kernel_launch(void* const* d_in, const int* in_sizes, int n_in,
                              void* d_out, int out_size, void* d_ws, size_t ws_size,
                              hipStream_t stream)
{
    const float* out0   = (const float*)d_in[0];
    const float* out1   = (const float*)d_in[1];
    const float* out2   = (const float*)d_in[2];
    const float* gamma0 = (const float*)d_in[3];
    const float* gamma1 = (const float*)d_in[4];
    const float* gamma2 = (const float*)d_in[5];
    const float* W_in1  = (const float*)d_in[6];
    const float* W_in2  = (const float*)d_in[8];
    const float* W_in3  = (const float*)d_in[10];
    const float* b_in1  = (const float*)d_in[7];
    const float* b_in2  = (const float*)d_in[9];
    const float* b_in3  = (const float*)d_in[11];
    const float* W_tr   = (const float*)d_in[12];
    const float* b_tr   = (const float*)d_in[13];
    const float* W_o1   = (const float*)d_in[14];
    const float* b_o1   = (const float*)d_in[15];
    const float* W_o2   = (const float*)d_in[16];
    const float* b_o2   = (const float*)d_in[17];
    const float* W_o3   = (const float*)d_in[18];
    const float* b_o3   = (const float*)d_in[19];
    float* outp = (float*)d_out;

    unsigned char* ws = (unsigned char*)d_ws;
    const size_t SZ_ACT  = (size_t)3 * NPIX * DCH * 2;   // 96 MB
    const size_t SZ_ACT8 = (size_t)3 * NPIX * DCH;       // 48 MB
    const size_t WB_BF16 = (size_t)(6 * WSQ + WTR) * 2;  // 7864320
    const size_t WB_FP8  = (size_t)(6 * WSQ + WTR);      // 3932160
    const size_t NEED    = 2 * SZ_ACT + SZ_ACT8 + WB_BF16 + WB_FP8 + 16384;
    const bool   big     = (ws_size >= NEED);

    // big layout: buf0 (96M: G bf16 channel-major) | P8 (48M: XbT8 then Htra8)
    //           | Q (96M: Hcat8 in first 48M) | weights | bias
    __hip_bfloat16* buf0 = (__hip_bfloat16*)ws;
    unsigned char*  P8   = ws + SZ_ACT;
    unsigned char*  Q    = ws + SZ_ACT + SZ_ACT8;
    unsigned char*  wtop = big ? (ws + 2 * SZ_ACT + SZ_ACT8) : (ws + 2 * SZ_ACT);
    __hip_bfloat16* Wb     = (__hip_bfloat16*)wtop;
    __hip_bfloat16* Wb_tr  = Wb + 3 * WSQ;
    __hip_bfloat16* Wb_o   = Wb_tr + WTR;
    unsigned char*  Wf8    = wtop + WB_BF16;
    unsigned char*  Win8   = Wf8;
    unsigned char*  Wtr8   = Wf8 + 3 * WSQ;
    unsigned char*  Wo8    = Wf8 + 3 * WSQ + WTR;
    float*          biasWS = (float*)(wtop + WB_BF16 + WB_FP8);

    const int NB = (6 * WSQ + WTR) >> 10;   // 3840
    cvt_all<<<2 * NB + 1, 256, 0, stream>>>(
        W_in1, W_in2, W_in3, W_tr, W_o1, W_o2, W_o3, Wb, Wf8,
        b_in1, b_in2, b_in3, b_o1, b_o2, b_o3, biasWS);

    stage_transpose<<<dim3(16, 8, 96), 256, 0, stream>>>(
        out0, out1, out2, gamma0, gamma1, gamma2,
        buf0, P8, big ? 0 : 1, big ? 1 : 0);

    if (big) {
        // GEMM-A (fp8 batched): XbT8 x W_in_i -> Hcat8[n][br*512+o]
        gemm_f8<<<dim3(1536), 256, 0, stream>>>(
            P8, DCH, Win8, DCH, biasWS, Q, 3 * DCH, 0,
            DCH, 4, 512, NPIX * DCH, WSQ, DCH, DCH, 1);
        // GEMM-B (fp8): Hcat8 x Wtr8 -> Htra8 (P8; XbT8 dead)
        gemm_f8<<<dim3(1536), 256, 0, stream>>>(
            Q, 3 * DCH, Wtr8, 3 * DCH, b_tr, P8, 3 * DCH, 0,
            3 * DCH, 12, 1536, 0, 0, 0, 0, 1);
        // GEMM-C (fp8 batched, TRANS OUT): Htra8 x W_out_i -> G bf16 [1536][NPIX]
        gemm_f8<<<dim3(1536), 256, 0, stream>>>(
            P8, 3 * DCH, Wo8, DCH, biasWS + 3 * DCH, buf0, NPIX, 0,
            DCH, 4, 512, DCH, WSQ, DCH, DCH, 2);
        final_fuse<<<dim3(NPIX / 256, DCH / 64), 256, 0, stream>>>(
            buf0, out0, out1, out2, gamma0, gamma1, gamma2, outp);
    } else {
        // fallback: all-bf16 two-buffer flow (R7)
        __hip_bfloat16* buf1 = (__hip_bfloat16*)(ws + SZ_ACT);
        gemm256<<<dim3(768), 512, 0, stream>>>(
            buf0, DCH, Wb, DCH, biasWS,
            buf1, 3 * DCH, 0, DCH, 2, 256, NPIX * DCH, WSQ, DCH, DCH, 0);
        gemm256<<<dim3(768), 512, 0, stream>>>(
            buf1, 3 * DCH, Wb_tr, 3 * DCH, b_tr,
            buf0, 3 * DCH, 0, 3 * DCH, 6, 768, 0, 0, 0, 0, 0);
        gemm256<<<dim3(768), 512, 0, stream>>>(
            buf0, 3 * DCH, Wb_o, DCH, biasWS + 3 * DCH,
            buf1, NPIX, 0, DCH, 2, 256, DCH, WSQ, DCH, DCH, 1);
        final_fuse<<<dim3(NPIX / 256, DCH / 64), 256, 0, stream>>>(
            buf1, out0, out1, out2, gamma0, gamma1, gamma2, outp);
    }
}